// Round 1
// baseline (2365.838 us; speedup 1.0000x reference)
//
#include <hip/hip_runtime.h>
#include <stdint.h>
#include <stddef.h>

#define CH    512   // channels
#define TT    32    // timesteps per block
#define NBLK  32    // number of blocks
#define NBATCH 32   // batch size
#define WPB   8     // workgroups per batch
#define CPW   64    // channels per workgroup
#define NTHR  256   // 4 waves: wave q = j-quarter, lane ci = channel-in-WG

// d_ws layout:
//   [0)                      int32 tspike[2][NBATCH][CH]   (double buffer, 128 KiB)
//   [2*NBATCH*CH*4)          uint32 cnt[NBATCH]            (barrier counters)

__global__ __launch_bounds__(NTHR, 1) void snn_kernel(
    const float* __restrict__ x,
    const float* __restrict__ beta_raw,
    const float* __restrict__ W,        // rec_weight, row-major [i][j]
    const float* __restrict__ p_raw,
    const float* __restrict__ b_raw,
    int*       __restrict__ tsp,        // [2][NBATCH][CH]
    unsigned*  __restrict__ cnt,        // [NBATCH]
    float*     __restrict__ out)
{
    __shared__ float rec_lds[4][CPW][33];   // +1 pad: (33*ci+t)%32 = (ci+t)%32 -> 2-way max (free)
    __shared__ int   lds_tj[CH];

    const int wg  = blockIdx.x;
    const int b   = wg & (NBATCH - 1);   // batch: wg%8==b%8 -> batch's WGs share an XCD
    const int k   = wg >> 5;             // channel chunk 0..7
    const int tid = threadIdx.x;
    const int q   = tid >> 6;            // j-quarter (one per wave)
    const int ci  = tid & 63;
    const int i   = k * CPW + ci;        // absolute channel

    // per-channel params (match reference clipping exactly)
    const float beta  = fminf(fmaxf(beta_raw[i], 0.001f), 0.999f);
    const float p     = fminf(fabsf(p_raw[i]), 0.999f);
    const float bb    = fminf(fmaxf(fabsf(b_raw[i]), 0.001f), 1.0f);
    const float inv_p = 1.0f / p;
    float p32;
    { float t2 = p*p, t4 = t2*t2, t8 = t4*t4, t16 = t8*t8; p32 = t16*t16; }

    // carry state per (b, channel): a_kernel[t] = p^(t+1) * a_mult
    float a_mult = 0.f;     // block 0: a_kernel = 0 -> v_th = 1 automatically
    float v_init = 0.f;
    int   zero_start = 0;   // zero x_slice for t < zero_start (refractory carry)

    const float* wrow = W + (size_t)i * CH;
    const float* xrow = x + (size_t)(b * CH + i) * (NBLK * TT);
    float*       orow = out + (size_t)(b * CH + i) * (NBLK * TT);
    unsigned*    cb   = cnt + b;

    for (int n = 0; n < NBLK; ++n) {
        if (n > 0) {
            // ---- per-batch barrier: wait until all 8 WGs finished step n-1 ----
            if (tid == 0) {
                const unsigned target = (unsigned)(WPB * n);
                while (__hip_atomic_load(cb, __ATOMIC_ACQUIRE, __HIP_MEMORY_SCOPE_AGENT) < target)
                    __builtin_amdgcn_s_sleep(2);
            }
            __syncthreads();
            __threadfence();   // acquire side: make peers' tspike stores visible

            // ---- load prev-block spike times (coherent loads), zero own rec rows ----
            const int* rd = tsp + ((n & 1) ? 0 : NBATCH * CH) + b * CH;
            for (int u = tid; u < CH; u += NTHR)
                lds_tj[u] = __hip_atomic_load(rd + u, __ATOMIC_RELAXED, __HIP_MEMORY_SCOPE_AGENT);
            #pragma unroll
            for (int t = 0; t < TT; ++t) rec_lds[q][ci][t] = 0.f;
            __syncthreads();

            // ---- gather: wave q accumulates its j-quarter of W into rec_lds[q][ci][*] ----
            const int j0 = q * (CH / 4);
            for (int jj = 0; jj < CH / 4; ++jj) {
                const int j  = j0 + jj;
                const int tj = lds_tj[j];      // wave-uniform -> uniform branch
                if (tj >= 0)
                    rec_lds[q][ci][tj] += wrow[j];
            }
            __syncthreads();
        }

        // ---- dynamics: wave 0 only (one thread per channel) ----
        if (q == 0) {
            float xv[TT];
            #pragma unroll
            for (int u = 0; u < TT / 4; ++u) {
                const float4 v = ((const float4*)(xrow + n * TT))[u];
                xv[4*u+0] = v.x; xv[4*u+1] = v.y; xv[4*u+2] = v.z; xv[4*u+3] = v.w;
            }
            float mem = 0.f, pc = p, pca = p;
            int t_first = -1;
            #pragma unroll
            for (int t = 0; t < TT; ++t) {
                float r = (n > 0) ? (rec_lds[0][ci][t] + rec_lds[1][ci][t]
                                   + rec_lds[2][ci][t] + rec_lds[3][ci][t]) : 0.f;
                float cur = (t >= zero_start) ? (xv[t] + r) : 0.f;
                if (t == 0) cur += beta * v_init;
                mem = beta * mem + cur;                 // leaky integrate (== K einsum)
                const float vth = 1.f + bb * pc * a_mult;
                if ((mem - vth > 0.f) && t_first < 0) { t_first = t; pca = pc; }
                pc *= p;
            }
            // spikes = 1 at first crossing only (z == 1)
            #pragma unroll
            for (int u = 0; u < TT / 4; ++u) {
                float4 v;
                v.x = (4*u+0 == t_first) ? 1.f : 0.f;
                v.y = (4*u+1 == t_first) ? 1.f : 0.f;
                v.z = (4*u+2 == t_first) ? 1.f : 0.f;
                v.w = (4*u+3 == t_first) ? 1.f : 0.f;
                ((float4*)(orow + n * TT))[u] = v;
            }
            // carry update
            if (t_first >= 0) {
                float pd = 1.f;                          // p^(31 - t_first)
                for (int m = 31 - t_first; m > 0; --m) pd *= p;
                a_mult = (pca * a_mult + inv_p) * pd;    // (a_kernel[tf] + 1/p) * p^decay
                v_init = 0.f;
                zero_start = t_first;
            } else {
                a_mult = p32 * a_mult;                   // a_kernel[-1]
                v_init = mem;                            // mem at t=31
                zero_start = 0;
            }
            if (n < NBLK - 1) {
                int* wr = tsp + ((n & 1) ? NBATCH * CH : 0) + b * CH;
                __hip_atomic_store(wr + i, t_first, __ATOMIC_RELAXED, __HIP_MEMORY_SCOPE_AGENT);
            }
        }

        // ---- arrive ----
        if (n < NBLK - 1) {
            __threadfence();   // release: drain this wave's tspike/out stores
            if (tid == 0)
                __hip_atomic_fetch_add(cb, 1u, __ATOMIC_RELEASE, __HIP_MEMORY_SCOPE_AGENT);
        }
    }
}

extern "C" void kernel_launch(void* const* d_in, const int* in_sizes, int n_in,
                              void* d_out, int out_size, void* d_ws, size_t ws_size,
                              hipStream_t stream) {
    (void)in_sizes; (void)n_in; (void)out_size;
    const float* x    = (const float*)d_in[0];
    const float* br   = (const float*)d_in[1];
    const float* W    = (const float*)d_in[2];
    const float* pr   = (const float*)d_in[3];
    const float* bbr  = (const float*)d_in[4];
    float* out = (float*)d_out;

    const size_t tsp_bytes = (size_t)2 * NBATCH * CH * sizeof(int);
    const size_t need = tsp_bytes + NBATCH * sizeof(unsigned);
    if (ws_size < need) return;  // fail loudly (output stays poisoned)

    int*      tsp = (int*)d_ws;
    unsigned* cnt = (unsigned*)((char*)d_ws + tsp_bytes);

    hipMemsetAsync(cnt, 0, NBATCH * sizeof(unsigned), stream);
    snn_kernel<<<NBATCH * WPB, NTHR, 0, stream>>>(x, br, W, pr, bbr, tsp, cnt, out);
}

// Round 2
// 1001.975 us; speedup vs baseline: 2.3612x; 2.3612x over previous
//
#include <hip/hip_runtime.h>
#include <stdint.h>
#include <stddef.h>

#define CH     512   // channels
#define TT     32    // timesteps per block
#define NBLK   32    // number of blocks
#define NBATCH 32    // batch size
#define NTHR   512   // one thread per channel, 8 waves
#define XS     33    // LDS stride for [CH][TT] arrays: (33i+t)%32=(i+t)%32 -> conflict-free

// ---------------- transpose W -> WT (coalesced gather loads) ----------------
__global__ __launch_bounds__(256) void transpose_k(const float* __restrict__ W,
                                                   float* __restrict__ WT) {
    __shared__ float tile[64][65];
    const int bx = blockIdx.x & 7, by = blockIdx.x >> 3;
    const int lx = threadIdx.x & 63, ly = threadIdx.x >> 6;
    for (int r = ly; r < 64; r += 4)
        tile[r][lx] = W[(size_t)(by * 64 + r) * CH + bx * 64 + lx];
    __syncthreads();
    for (int r = ly; r < 64; r += 4)
        WT[(size_t)(bx * 64 + r) * CH + by * 64 + lx] = tile[lx][r];
}

// ---------------- main: one workgroup per batch, no global sync ----------------
__global__ __launch_bounds__(NTHR, 1) void snn_kernel(
    const float* __restrict__ x,
    const float* __restrict__ beta_raw,
    const float* __restrict__ Wmat,      // WT if coalesced, else W
    const float* __restrict__ p_raw,
    const float* __restrict__ b_raw,
    float*       __restrict__ out,
    const int coalesced)
{
    __shared__ float x_stage[CH * XS];            // 67584 B, coalesced-staged x block
    __shared__ float rec_s[CH * XS];              // 67584 B, per-t recurrent sums
    __shared__ int   tf_lds[CH];                  // spike times this block
    __shared__ int   wcnt[8][32];                 // per-wave histogram
    __shared__ int   woff[8][32];                 // per-wave exclusive offsets
    __shared__ int   start_s[TT + 1];             // bucket starts (prefix over t)
    __shared__ alignas(16) int bucket[CH];        // t-sorted spike list: (t<<16)|j

    const int b   = blockIdx.x;
    const int tid = threadIdx.x;
    const int i   = tid;                          // channel
    const int l   = tid & 63;
    const int w   = tid >> 6;

    // params (match reference clipping exactly)
    const float beta  = fminf(fmaxf(beta_raw[i], 0.001f), 0.999f);
    const float p     = fminf(fabsf(p_raw[i]), 0.999f);
    const float bb    = fminf(fmaxf(fabsf(b_raw[i]), 0.001f), 1.0f);
    const float inv_p = 1.0f / p;
    float p32; { float t2 = p*p, t4 = t2*t2, t8 = t4*t4, t16 = t8*t8; p32 = t16*t16; }

    // carry state
    float a_mult = 0.f, v_init = 0.f;
    int   zero_start = 0;

    const size_t xbase = ((size_t)(b * CH) << 10);      // b*CH*1024 floats
    const int    c0    = (w << 6) + (l >> 3);           // staging: 8 lanes per channel
    const int    sub   = l & 7, tb = sub << 2;

    // coalesced x staging for block n
    auto load_x = [&](int n) {
        #pragma unroll
        for (int it = 0; it < 8; ++it) {
            const int c = c0 + (it << 3);
            const float4 v = *(const float4*)(x + xbase + ((size_t)c << 10) + (n << 5) + tb);
            const int a = c * XS + tb;
            x_stage[a] = v.x; x_stage[a+1] = v.y; x_stage[a+2] = v.z; x_stage[a+3] = v.w;
        }
    };
    auto wload = [&](int e) -> float {
        const int j = e & 1023;
        return coalesced ? Wmat[((size_t)j << 9) + i]   // WT[j][i]: lanes consecutive
                         : Wmat[((size_t)i << 9) + j];  // fallback, uncoalesced
    };

    load_x(0);
    int L = 0;
    __syncthreads();

    const int roff = i * XS;
    const unsigned long long lowmask = (1ull << l) - 1ull;

    for (int n = 0; n < NBLK; ++n) {
        // ---- phase 1: gather prev-block spikes into rec_s[i][t] (t-sorted flat list) ----
        {
            float racc = 0.f;
            int cur_t = 0;
// flush per-t sums up to (not incl.) tt; covers empty t's with zeros
#define FLUSH_TO(tt) while (cur_t < (tt)) { rec_s[roff + cur_t] = racc; racc = 0.f; ++cur_t; }
            int u = 0;
            while (u + 8 <= L) {   // chunk of 8: loads issued before first use
                const int4 ea = *(const int4*)&bucket[u];
                const int4 eb = *(const int4*)&bucket[u + 4];
                const float f0 = wload(ea.x), f1 = wload(ea.y), f2 = wload(ea.z), f3 = wload(ea.w);
                const float f4 = wload(eb.x), f5 = wload(eb.y), f6 = wload(eb.z), f7 = wload(eb.w);
                FLUSH_TO(ea.x >> 16); racc += f0;
                FLUSH_TO(ea.y >> 16); racc += f1;
                FLUSH_TO(ea.z >> 16); racc += f2;
                FLUSH_TO(ea.w >> 16); racc += f3;
                FLUSH_TO(eb.x >> 16); racc += f4;
                FLUSH_TO(eb.y >> 16); racc += f5;
                FLUSH_TO(eb.z >> 16); racc += f6;
                FLUSH_TO(eb.w >> 16); racc += f7;
                u += 8;
            }
            while (u < L) {
                const int e = bucket[u++];
                const float f = wload(e);
                FLUSH_TO(e >> 16);
                racc += f;
            }
            FLUSH_TO(TT);
#undef FLUSH_TO
        }

        // ---- phase 2: membrane recurrence, fully unrolled (static LDS indices) ----
        float mem = 0.f, pc = p, pca = p;
        int t_first = -1;
        #pragma unroll
        for (int t = 0; t < TT; ++t) {
            const float xv = x_stage[roff + t];
            const float r  = rec_s[roff + t];
            float cur = (t >= zero_start) ? (xv + r) : 0.f;
            if (t == 0) cur += beta * v_init;
            mem = beta * mem + cur;
            const float vth = 1.f + bb * pc * a_mult;
            if ((mem - vth > 0.f) && t_first < 0) { t_first = t; pca = pc; }
            pc *= p;
        }

        // carry update
        if (t_first >= 0) {
            float pd = 1.f;                          // p^(31 - t_first)
            for (int m = 31 - t_first; m > 0; --m) pd *= p;
            a_mult = (pca * a_mult + inv_p) * pd;
            v_init = 0.f; zero_start = t_first;
        } else {
            a_mult = p32 * a_mult;
            v_init = mem; zero_start = 0;
        }

        // ---- phase 3: deterministic ballot-rank histogram ----
        tf_lds[i] = t_first;
        int myrank = 0;
        #pragma unroll
        for (int t = 0; t < TT; ++t) {
            const unsigned long long bal = __ballot(t_first == t);
            if (t_first == t) myrank = __popcll(bal & lowmask);
            if (l == t) wcnt[w][t] = (int)__popcll(bal);
        }
        __syncthreads();   // A: dynamics reads + wcnt writes complete

        // ---- phase 4: output write + x reload (all waves); wave0: prefix scans ----
        #pragma unroll
        for (int it = 0; it < 8; ++it) {
            const int c = c0 + (it << 3);
            const int tfc = tf_lds[c];
            float4 v;
            v.x = (tb     == tfc) ? 1.f : 0.f;
            v.y = (tb + 1 == tfc) ? 1.f : 0.f;
            v.z = (tb + 2 == tfc) ? 1.f : 0.f;
            v.w = (tb + 3 == tfc) ? 1.f : 0.f;
            *(float4*)(out + xbase + ((size_t)c << 10) + (n << 5) + tb) = v;
        }
        if (n + 1 < NBLK) load_x(n + 1);
        if (w == 0) {
            const int t = l & 31;
            int s = 0;
            #pragma unroll
            for (int ww = 0; ww < 8; ++ww) {
                if (l < 32) woff[ww][t] = s;     // exclusive over waves
                s += wcnt[ww][t];
            }
            int v = s;                            // inclusive scan over t (lanes 0..31)
            #pragma unroll
            for (int d = 1; d < 32; d <<= 1) {
                const int o = __shfl_up(v, (unsigned)d, 64);
                if (l >= d) v += o;
            }
            if (l < 32) start_s[t + 1] = v;
            if (l == 0) start_s[0] = 0;
        }
        __syncthreads();   // B: scans ready, gather of this block done

        // ---- phase 5: scatter t-sorted spike list for next block ----
        if (t_first >= 0) {
            const int pos = start_s[t_first] + woff[w][t_first] + myrank;
            bucket[pos] = (t_first << 16) | i;
        }
        L = start_s[TT];
        __syncthreads();   // C: bucket ready for next iteration
    }
}

extern "C" void kernel_launch(void* const* d_in, const int* in_sizes, int n_in,
                              void* d_out, int out_size, void* d_ws, size_t ws_size,
                              hipStream_t stream) {
    (void)in_sizes; (void)n_in; (void)out_size;
    const float* x   = (const float*)d_in[0];
    const float* br  = (const float*)d_in[1];
    const float* W   = (const float*)d_in[2];
    const float* pr  = (const float*)d_in[3];
    const float* bbr = (const float*)d_in[4];
    float* out = (float*)d_out;

    int coalesced = 0;
    const float* Wmat = W;
    if (ws_size >= (size_t)CH * CH * sizeof(float)) {
        float* WT = (float*)d_ws;
        transpose_k<<<64, 256, 0, stream>>>(W, WT);
        Wmat = WT;
        coalesced = 1;
    }
    snn_kernel<<<NBATCH, NTHR, 0, stream>>>(x, br, Wmat, pr, bbr, out, coalesced);
}

// Round 3
// 965.856 us; speedup vs baseline: 2.4495x; 1.0374x over previous
//
#include <hip/hip_runtime.h>
#include <stdint.h>
#include <stddef.h>

#define CH     512   // channels
#define TT     32    // timesteps per block
#define NBLK   32    // number of blocks
#define NBATCH 32    // batch size
#define NTHR   1024  // 16 waves: waves 0-7 "low" (front gather + dynamics), 8-15 "high" (back gather + epilogue)
#define XS     33    // LDS stride: lane-stride 33 words -> conflict-free

// ---------------- transpose W -> WT (coalesced gather loads) ----------------
__global__ __launch_bounds__(256) void transpose_k(const float* __restrict__ W,
                                                   float* __restrict__ WT) {
    __shared__ float tile[64][65];
    const int bx = blockIdx.x & 7, by = blockIdx.x >> 3;
    const int lx = threadIdx.x & 63, ly = threadIdx.x >> 6;
    for (int r = ly; r < 64; r += 4)
        tile[r][lx] = W[(size_t)(by * 64 + r) * CH + bx * 64 + lx];
    __syncthreads();
    for (int r = ly; r < 64; r += 4)
        WT[(size_t)(bx * 64 + r) * CH + by * 64 + lx] = tile[lx][r];
}

// entry encoding: e = (j << 11) | t ; byte offset of WT row j = j*2048 = e & 0xFF800 (garbage-safe: always < 1 MiB)
#define WLD(e) (COAL ? *(const float*)(wb + ((e) & 0xFF800)) \
                     : *(const float*)(wb + (((unsigned)((e) & 0xFF800)) >> 9)))
#define PROC1(e, f) { const int te_ = (e) & 31; \
    while (cur_t < te_) { rec_s[roff + cur_t] = racc; racc = 0.f; ++cur_t; } \
    racc += (f); }
#define LOAD16(uu, E, F) { \
    _Pragma("unroll") for (int k_ = 0; k_ < 16; ++k_) E[k_] = bucket[(uu) + k_]; \
    _Pragma("unroll") for (int k_ = 0; k_ < 16; ++k_) F[k_] = WLD(E[k_]); }
#define PROC16(E, F) { \
    _Pragma("unroll") for (int k_ = 0; k_ < 16; ++k_) PROC1(E[k_], F[k_]) }
#define PROCG(E, F, cnt) { \
    _Pragma("unroll") for (int k_ = 0; k_ < 16; ++k_) if (k_ < (cnt)) PROC1(E[k_], F[k_]) }

template <int COAL>
__global__ __launch_bounds__(NTHR, 4) void snn_kernel(
    const float* __restrict__ x,
    const float* __restrict__ beta_raw,
    const float* __restrict__ Wmat,      // WT if COAL, else row-major W
    const float* __restrict__ p_raw,
    const float* __restrict__ b_raw,
    float*       __restrict__ out)
{
    __shared__ float rec_s[CH * XS];     // 67584 B  per-t recurrent sums
    __shared__ float x_stage[CH * XS];   // 67584 B  staged x block
    __shared__ int   tf_lds[CH];
    __shared__ int   wcnt[8][32];
    __shared__ int   woff[8][32];
    __shared__ int   start_s[TT + 1];
    __shared__ int   bucket[544];        // t-sorted spike list (+pad for over-read)
    __shared__ int   sp_info[3];         // [L, m_split, t_split]

    const int b   = blockIdx.x;
    const int tid = threadIdx.x;
    const int cid = tid & (CH - 1);
    const int low = (tid < CH);
    const int l   = tid & 63;
    const int w   = tid >> 6;            // 0..15

    const size_t base = ((size_t)(b * CH)) << 10;          // floats
    const char*  wb   = COAL ? ((const char*)Wmat + (cid << 2))
                             : ((const char*)Wmat + ((size_t)cid << 11));
    const int    roff = cid * XS;
    const unsigned long long lowmask = (1ull << l) - 1ull;

    // per-channel params + carry (low threads only)
    float beta = 0.f, p = 0.f, bb = 0.f, inv_p = 0.f, p32 = 0.f;
    float a_mult = 0.f, v_init = 0.f;
    int   zero_start = 0;
    if (low) {
        beta  = fminf(fmaxf(beta_raw[cid], 0.001f), 0.999f);
        p     = fminf(fabsf(p_raw[cid]), 0.999f);
        bb    = fminf(fmaxf(fabsf(b_raw[cid]), 0.001f), 1.0f);
        inv_p = 1.0f / p;
        float t2 = p * p, t4 = t2 * t2, t8 = t4 * t4, t16 = t8 * t8;
        p32 = t16 * t16;
    }

    // epilogue-channel mapping (used by high waves; 8 lanes per channel)
    const int ch0 = ((w & 7) << 6) + (l >> 3);
    const int tb  = (l & 7) << 2;

    if (!low) {   // stage x block 0
        #pragma unroll
        for (int it = 0; it < 8; ++it) {
            const int c = ch0 + (it << 3);
            const float4 v = *(const float4*)(x + base + ((size_t)c << 10) + tb);
            const int a = c * XS + tb;
            x_stage[a] = v.x; x_stage[a+1] = v.y; x_stage[a+2] = v.z; x_stage[a+3] = v.w;
        }
    }
    if (tid == 0) { sp_info[0] = 0; sp_info[1] = 0; sp_info[2] = 0; }
    __syncthreads();

    for (int n = 0; n < NBLK; ++n) {
        // ---- phase 1: split gather into rec_s[i][t] ----
        {
            const int Lc = sp_info[0], mm = sp_info[1], ts = sp_info[2];
            int       cur_t = low ? 0 : ts;
            const int tend  = low ? ts : TT;
            int       u     = low ? 0 : mm;
            int       remaining = (low ? mm : Lc) - u;
            float racc = 0.f;
            if (remaining > 0) {
                int EA[16]; float FA[16]; int EB[16]; float FB[16];
                LOAD16(u, EA, FA);
                while (true) {
                    if (remaining > 16) LOAD16(u + 16, EB, FB);
                    if (remaining >= 16) { PROC16(EA, FA); } else { PROCG(EA, FA, remaining); }
                    u += 16; remaining -= 16;
                    if (remaining <= 0) break;
                    if (remaining > 16) LOAD16(u + 16, EA, FA);
                    if (remaining >= 16) { PROC16(EB, FB); } else { PROCG(EB, FB, remaining); }
                    u += 16; remaining -= 16;
                    if (remaining <= 0) break;
                }
            }
            while (cur_t < tend) { rec_s[roff + cur_t] = racc; racc = 0.f; ++cur_t; }
        }
        __syncthreads();   // D: rec_s complete

        // ---- phase 2: dynamics + ballot (low waves) ----
        int t_first = -1, myrank = 0;
        if (low) {
            float mem = 0.f, pc = p, pca = p;
            #pragma unroll
            for (int t = 0; t < TT; ++t) {
                const float xv = x_stage[roff + t];
                const float r  = rec_s[roff + t];
                float cur = (t >= zero_start) ? (xv + r) : 0.f;
                if (t == 0) cur += beta * v_init;
                mem = beta * mem + cur;
                const float vth = 1.f + bb * pc * a_mult;
                if ((mem - vth > 0.f) && t_first < 0) { t_first = t; pca = pc; }
                pc *= p;
            }
            if (t_first >= 0) {
                float pd = 1.f;
                for (int q2 = 31 - t_first; q2 > 0; --q2) pd *= p;
                a_mult = (pca * a_mult + inv_p) * pd;
                v_init = 0.f; zero_start = t_first;
            } else {
                a_mult = p32 * a_mult;
                v_init = mem; zero_start = 0;
            }
            tf_lds[cid] = t_first;
            #pragma unroll
            for (int t = 0; t < TT; ++t) {
                const unsigned long long bal = __ballot(t_first == t);
                if (t_first == t) myrank = (int)__popcll(bal & lowmask);
                if (l == t) wcnt[w][t] = (int)__popcll(bal);
            }
        }
        __syncthreads();   // A: tf_lds + wcnt ready

        // ---- phase 3a: epilogue on high waves (stores + next-x staging) ----
        if (!low) {
            #pragma unroll
            for (int it = 0; it < 8; ++it) {
                const int c = ch0 + (it << 3);
                const int tfc = tf_lds[c];
                float4 v;
                v.x = (tb     == tfc) ? 1.f : 0.f;
                v.y = (tb + 1 == tfc) ? 1.f : 0.f;
                v.z = (tb + 2 == tfc) ? 1.f : 0.f;
                v.w = (tb + 3 == tfc) ? 1.f : 0.f;
                *(float4*)(out + base + ((size_t)c << 10) + (n << 5) + tb) = v;
            }
            if (n + 1 < NBLK) {
                #pragma unroll
                for (int it = 0; it < 8; ++it) {
                    const int c = ch0 + (it << 3);
                    const float4 v = *(const float4*)(x + base + ((size_t)c << 10) + ((n + 1) << 5) + tb);
                    const int a2 = c * XS + tb;
                    x_stage[a2] = v.x; x_stage[a2+1] = v.y; x_stage[a2+2] = v.z; x_stage[a2+3] = v.w;
                }
            }
        }
        // ---- phase 3b: scans + split point (wave 0) ----
        if (w == 0) {
            const int t = l & 31;
            int s = 0;
            #pragma unroll
            for (int ww = 0; ww < 8; ++ww) {
                if (l < 32) woff[ww][t] = s;
                s += wcnt[ww][t];
            }
            int v = s;
            #pragma unroll
            for (int d = 1; d < 32; d <<= 1) {
                const int o = __shfl_up(v, (unsigned)d, 64);
                if (l >= d) v += o;
            }
            if (l < 32) start_s[t + 1] = v;
            if (l == 0) start_s[0] = 0;
            const int excl = v - s;                       // exclusive prefix = start_s[t]
            const int Ltot = __shfl(v, 31, 64);
            const int hf   = (Ltot + 1) >> 1;
            const unsigned long long bal = __ballot((l < 32) && (excl >= hf));
            const int tstar = bal ? (int)(__ffsll((unsigned long long)bal) - 1) : TT;
            const int msp   = (tstar < TT) ? __shfl(excl, tstar, 64) : Ltot;
            if (l == 0) { sp_info[0] = Ltot; sp_info[1] = msp; sp_info[2] = tstar; }
        }
        __syncthreads();   // B: scans + split ready

        // ---- phase 4: scatter t-sorted spike list for next block ----
        if (low && t_first >= 0) {
            const int pos = start_s[t_first] + woff[w][t_first] + myrank;
            bucket[pos] = (cid << 11) | t_first;
        }
        __syncthreads();   // C: bucket ready
    }
}

extern "C" void kernel_launch(void* const* d_in, const int* in_sizes, int n_in,
                              void* d_out, int out_size, void* d_ws, size_t ws_size,
                              hipStream_t stream) {
    (void)in_sizes; (void)n_in; (void)out_size;
    const float* x   = (const float*)d_in[0];
    const float* br  = (const float*)d_in[1];
    const float* W   = (const float*)d_in[2];
    const float* pr  = (const float*)d_in[3];
    const float* bbr = (const float*)d_in[4];
    float* out = (float*)d_out;

    if (ws_size >= (size_t)CH * CH * sizeof(float)) {
        float* WT = (float*)d_ws;
        transpose_k<<<64, 256, 0, stream>>>(W, WT);
        snn_kernel<1><<<NBATCH, NTHR, 0, stream>>>(x, br, WT, pr, bbr, out);
    } else {
        snn_kernel<0><<<NBATCH, NTHR, 0, stream>>>(x, br, W, pr, bbr, out);
    }
}